// Round 9
// baseline (321.393 us; speedup 1.0000x reference)
//
#include <hip/hip_runtime.h>
#include <hip/hip_bf16.h>

constexpr int NN = 100000;   // nodes
constexpr int NE = 1600000;  // edges
constexpr int NF = 64;       // input features
constexpr int NH = 16;       // hidden

constexpr int NPB  = 128;                      // nodes per bucket (dst>>7 / dst&127)
constexpr int LB   = 7;                        // log2(NPB)
constexpr int NBKT = (NN + NPB - 1) / NPB;     // 782 buckets
constexpr int CAP  = 2560;                     // per-bucket edge capacity (mean 2046, +11 sigma)
constexpr int TB   = 512;                      // fused-kernel block size (8 waves)
constexpr int CHUNK = 8192;                    // edges per bucket-role block (16 edges/thread)
constexpr int NBF   = (NE + CHUNK - 1) / CHUNK;   // 196 bucket-role blocks / fragments
constexpr int NGT   = (NN + TB - 1) / TB;         // 196 gemm tiles (512 nodes each)
constexpr int FD = NBKT + 1;                      // directory rows (783): bucket starts + total

// bucket-role LDS: srk 16K(u16) + lcnt 3.1K + fscan 3.1K + wsum 32B = ~22.8 KB
constexpr int SMEM_BYTES = CHUNK * 2 + NBKT * 4 + FD * 4 + 32;

__device__ __forceinline__ float bf16_to_f32(unsigned short u) {
    return __uint_as_float(((unsigned int)u) << 16);
}
__device__ __forceinline__ unsigned short f32_to_bf16(float f) {
    __hip_bfloat16 hb = __float2bfloat16(f);   // RNE
    return *reinterpret_cast<unsigned short*>(&hb);
}

// Fused front-end, 512 threads, 392 blocks — R3 GEOMETRY, byte-preserved.
// k_fused design space is EXHAUSTED at ~43 µs: CHUNK 4096 (R7: 63 µs),
// CHUNK 6250/512-block pairing (R4: 62 µs), TB 1024 (R2: 53-59 µs),
// zero-global-read pass B (R6: FETCH -10 MB, duration flat) all regressed
// or were neutral. Per-block fixed costs (counter zero + 782-scan + export)
// rival per-edge costs; 8192/512 balances them. DO NOT REVISIT GEOMETRY.
// R1 lesson: GEMM 2-thread split doubles load requests and regresses.
// R8 lesson: hipLaunchCooperativeKernel crashes the harness (graph capture /
// co-residency) — NEVER use cooperative launch here.
// NOTE (R12 lesson): do NOT add per-thread accumulator arrays or float4
// weight indexing here — both spill (VGPR 56 -> 128, scratch traffic 670 MB).
__global__ __launch_bounds__(TB)
void k_fused(const float* __restrict__ x,
             const float* __restrict__ Wl1,
             const float* __restrict__ Wr1,
             unsigned short* __restrict__ p,
             float* __restrict__ r,
             const int* __restrict__ ei, const float* __restrict__ As,
             const float* __restrict__ ws,
             unsigned int* __restrict__ gchunk, int* __restrict__ fdirT)
{
    __shared__ __align__(16) char smem[SMEM_BYTES];
    int b    = blockIdx.x;
    int role = (b < NBF) ? 1 : 0;          // 1 = bucket, 0 = gemm
    int rb   = role ? b : b - NBF;
    int tid  = threadIdx.x;

    if (role == 0) {
        // ---- GEMM role: nodes rb*512 .. rb*512+511, 1 thread per node ----
        float* sW = (float*)smem;
        for (int i = tid; i < NF * NH; i += TB) {
            sW[i]           = Wl1[i];
            sW[NF * NH + i] = Wr1[i];
        }
        __syncthreads();

        int n = rb * TB + tid;
        if (n >= NN) return;

        float aL[NH], aR[NH];
#pragma unroll
        for (int j = 0; j < NH; ++j) { aL[j] = 0.f; aR[j] = 0.f; }

        const float4* xr = reinterpret_cast<const float4*>(x + (size_t)n * NF);
#pragma unroll
        for (int k4 = 0; k4 < NF / 4; ++k4) {
            float4 v = xr[k4];
            float xs[4] = {v.x, v.y, v.z, v.w};
#pragma unroll
            for (int t2 = 0; t2 < 4; ++t2) {
                const float* wl = &sW[(k4 * 4 + t2) * NH];
                const float* wr = &sW[NF * NH + (k4 * 4 + t2) * NH];
#pragma unroll
                for (int j = 0; j < NH; ++j) {
                    aL[j] = fmaf(xs[t2], wl[j], aL[j]);
                    aR[j] = fmaf(xs[t2], wr[j], aR[j]);
                }
            }
        }

        unsigned int pu[8];
#pragma unroll
        for (int j2 = 0; j2 < 8; ++j2)
            pu[j2] = (unsigned int)f32_to_bf16(aL[2*j2]) |
                     ((unsigned int)f32_to_bf16(aL[2*j2+1]) << 16);
        uint4* pp = reinterpret_cast<uint4*>(p + (size_t)n * NH);
        pp[0] = make_uint4(pu[0], pu[1], pu[2], pu[3]);
        pp[1] = make_uint4(pu[4], pu[5], pu[6], pu[7]);

        float4* rp = reinterpret_cast<float4*>(r + (size_t)n * NH);
#pragma unroll
        for (int j4 = 0; j4 < NH / 4; ++j4)
            rp[j4] = make_float4(aR[j4*4], aR[j4*4+1], aR[j4*4+2], aR[j4*4+3]);
    } else {
        // ---- Bucket role: edges rb*CHUNK .. +CHUNK ----
        unsigned short* srk  = (unsigned short*)smem;        // 16-bit rank, 0xFFFF=drop
        int* lcnt  = (int*)(smem + CHUNK * 2);               // NBKT counters
        int* fscan = lcnt + NBKT;                            // FD exclusive scan
        int* wsum  = fscan + FD;                             // 8 wave sums

        for (int i = tid; i < NBKT; i += TB) lcnt[i] = 0;
        __syncthreads();

        int base = rb * CHUNK;
        float w0 = ws[0], w1 = ws[1];

        // pass A: mask + per-bucket rank (the count atomic's return IS the rank)
#pragma unroll
        for (int j = 0; j < CHUNK / TB; ++j) {
            int idx = j * TB + tid;
            int e = base + idx;
            unsigned short rk = 0xFFFFu;
            if (e < NE) {
                float ewm = w0 * As[e] + w1 * As[NE + e];
                if (ewm != 0.f)
                    rk = (unsigned short)atomicAdd(&lcnt[ei[NE + e] >> LB], 1); // <8192
            }
            srk[idx] = rk;
        }
        __syncthreads();

        // exclusive scan of 782 counters: thread t owns entries 2t, 2t+1;
        // per-thread sums scanned with wave shuffles (1 barrier)
        {
            int loc[2]; int s0 = 0;
#pragma unroll
            for (int g = 0; g < 2; ++g) {
                int idx = tid * 2 + g;
                int v = (idx < NBKT) ? lcnt[idx] : 0;
                loc[g] = s0; s0 += v;
            }
            int lane = tid & 63, w = tid >> 6;
            int si = s0;
#pragma unroll
            for (int off = 1; off < 64; off <<= 1) {
                int u = __shfl_up(si, off);
                if (lane >= off) si += u;
            }
            if (lane == 63) wsum[w] = si;
            __syncthreads();
            int bse = 0;
            for (int i = 0; i < w; ++i) bse += wsum[i];
            int excl = bse + si - s0;      // exclusive scan of per-thread sums
#pragma unroll
            for (int g = 0; g < 2; ++g) {
                int idx = tid * 2 + g;
                if (idx < NBKT) fscan[idx] = excl + loc[g];
            }
            if (tid == TB - 1) fscan[NBKT] = bse + si;
        }
        __syncthreads();

        // export directory column rb (transposed: [bucket][fragment])
        for (int i = tid; i < FD; i += TB)
            fdirT[(size_t)i * NBF + rb] = fscan[i];

        // pass B: re-read ei (L2-hot, measured free in R6), place sorted into
        // the block-private region (dense, line-clean writes)
#pragma unroll
        for (int j = 0; j < CHUNK / TB; ++j) {
            int idx = j * TB + tid;
            unsigned short rk = srk[idx];
            if (rk != 0xFFFFu) {
                int e   = base + idx;
                int dst = ei[NE + e];
                int bk  = dst >> LB;
                gchunk[(size_t)rb * CHUNK + fscan[bk] + rk] =
                    ((unsigned)ei[e] << LB) | (unsigned)(dst & (NPB - 1));
            }
        }
    }
}

// Layer-1 aggregation (R9 redesign): NO dl-sort. Stage this bucket's 196
// fragments into LDS (same directory gather as R3), then accumulate straight
// into a sacc[128][16] f32 LDS table via ds_add_f32 (unsafeAtomicAdd):
// 32 16-lane groups stride the staged edges — perfectly balanced, zero
// divergence (replaces hist+scan+scatter (3 LDS passes) + the serial
// per-node loop whose wave time was max-over-16 Poisson degrees).
// Bank math: addr (dl*16+k), bank = k + 16*(dl&1) -> collisions need same k
// AND same dl parity (2-way is free per m136); same-address needs same dl.
// Exports the UNSORTED staged list + count for k_agg2 (which also no longer
// needs segments). Epilogue: h = relu(sacc + r + bl1); q = h.Wl2;
// out = h.Wr2 + bl2.
__global__ __launch_bounds__(512)
void k_agg1(const int* __restrict__ fdirT, const unsigned int* __restrict__ gchunk,
            unsigned int* __restrict__ bmem, int* __restrict__ bcnt,
            const unsigned short* __restrict__ p, const float* __restrict__ r,
            const float* __restrict__ bl1, const float* __restrict__ Wl2,
            const float* __restrict__ bl2, const float* __restrict__ Wr2,
            float* __restrict__ q, float* __restrict__ out)
{
    __shared__ unsigned int sbm[CAP];       // 10 KB staged bucket (unsorted)
    __shared__ float sacc[NPB * NH];        // 8 KB accumulation table
    __shared__ int fstart[NBF];             // fragment start in gchunk row
    __shared__ int foff[NBF + 1];           // exclusive scan of fragment sizes
    __shared__ int wsum8[8];

    int b = blockIdx.x;
    int tid = threadIdx.x;

    // zero the accumulation table (2048 floats, 4 per thread)
#pragma unroll
    for (int j = 0; j < NPB * NH / 512; ++j)
        sacc[j * 512 + tid] = 0.f;

    // fragment directory: coalesced rows b and b+1 of fdirT; wave-shuffle scan
    {
        int sz = 0;
        if (tid < NBF) {
            int s0 = fdirT[(size_t)b * NBF + tid];
            int s1 = fdirT[(size_t)(b + 1) * NBF + tid];
            fstart[tid] = s0;
            sz = s1 - s0;
        }
        int lane = tid & 63, w = tid >> 6;
        int si = sz;
#pragma unroll
        for (int off = 1; off < 64; off <<= 1) {
            int u = __shfl_up(si, off);
            if (lane >= off) si += u;
        }
        if (lane == 63) wsum8[w] = si;
        __syncthreads();
        int bse = 0;
        for (int i = 0; i < w; ++i) bse += wsum8[i];
        if (tid < NBF) foff[tid] = bse + si - sz;   // exclusive
        if (tid == 511) foff[NBF] = bse + si;
    }
    __syncthreads();

    int cnt = min(foff[NBF], CAP);

    // stage: 32 16-lane groups; contiguous reads from gchunk
    {
        int grp = tid >> 4, k = tid & 15;
        for (int f = grp; f < NBF; f += 32) {
            int o  = foff[f];
            int sz = foff[f + 1] - o;
            int s  = fstart[f];
            const unsigned int* src = gchunk + (size_t)f * CHUNK + s;
            int lim = min(sz, CAP - o);
            for (int j = k; j < lim; j += 16)
                sbm[o + j] = src[j];
        }
    }
    __syncthreads();

    // export unsorted list + count for k_agg2 (drains while we accumulate)
    for (int i = tid; i < cnt; i += 512)
        bmem[(size_t)b * CAP + i] = sbm[i];
    if (tid == 0) bcnt[b] = cnt;

    // accumulate: group g takes edges g, g+32, g+64, ... (balanced, no
    // divergence); lane k owns feature k; 2-edge unroll for load ILP
    {
        int grp = tid >> 4, k = tid & 15;
        int i = grp;
        for (; i + 32 < cnt; i += 64) {
            unsigned wa = sbm[i];
            unsigned wb = sbm[i + 32];
            float va = bf16_to_f32(p[(size_t)(wa >> LB) * NH + k]);
            float vb = bf16_to_f32(p[(size_t)(wb >> LB) * NH + k]);
            unsafeAtomicAdd(&sacc[(wa & (NPB - 1)) * NH + k], va);
            unsafeAtomicAdd(&sacc[(wb & (NPB - 1)) * NH + k], vb);
        }
        if (i < cnt) {
            unsigned wa = sbm[i];
            float va = bf16_to_f32(p[(size_t)(wa >> LB) * NH + k]);
            unsafeAtomicAdd(&sacc[(wa & (NPB - 1)) * NH + k], va);
        }
    }
    __syncthreads();

    // epilogue — group g owns nodes 4g..4g+3, lane k feature k
    {
        int g = tid >> 4, k = tid & 15;
        int n0 = b * NPB;
#pragma unroll
        for (int jj = 0; jj < 4; ++jj) {
            int nl = g * 4 + jj;
            int n = n0 + nl;
            if (n < NN) {
                float h = sacc[nl * NH + k] + r[(size_t)n * NH + k] + bl1[k];
                h = h > 0.f ? h : 0.f;
                float qv = h * Wl2[k];
                float sv = h * Wr2[k];
#pragma unroll
                for (int m = 8; m >= 1; m >>= 1) {
                    qv += __shfl_xor(qv, m);
                    sv += __shfl_xor(sv, m);
                }
                if (k == 0) {
                    q[n]   = qv;
                    out[n] = sv + bl2[0];
                }
            }
        }
    }
}

// Layer-2 aggregation (R9 redesign): per-bucket block, 512 threads. Reads the
// unsorted bmem row coalesced, gathers q[src] (400 KB, L2-resident), and
// ds_add_f32-accumulates into sacc2[dl] (64 lanes over 128 counters — low
// contention). One coalesced out[] += at the end. Replaces the per-node
// segment walk (no gsoff, no sort dependency).
__global__ __launch_bounds__(512)
void k_agg2(const unsigned int* __restrict__ bmem, const int* __restrict__ bcnt,
            const float* __restrict__ q, float* __restrict__ out)
{
    __shared__ float sacc2[NPB];
    __shared__ int scnt;

    int b = blockIdx.x;
    int tid = threadIdx.x;
    if (tid == 0) scnt = bcnt[b];
    if (tid < NPB) sacc2[tid] = 0.f;
    __syncthreads();

    int cnt = scnt;
    const unsigned int* bm = bmem + (size_t)b * CAP;

    int i = tid;
    for (; i + 512 < cnt; i += 1024) {
        unsigned wa = bm[i];
        unsigned wb = bm[i + 512];
        float va = q[wa >> LB];
        float vb = q[wb >> LB];
        unsafeAtomicAdd(&sacc2[wa & (NPB - 1)], va);
        unsafeAtomicAdd(&sacc2[wb & (NPB - 1)], vb);
    }
    if (i < cnt) {
        unsigned wa = bm[i];
        unsafeAtomicAdd(&sacc2[wa & (NPB - 1)], q[wa >> LB]);
    }
    __syncthreads();

    if (tid < NPB) {
        int n = b * NPB + tid;
        if (n < NN) out[n] += sacc2[tid];
    }
}

extern "C" void kernel_launch(void* const* d_in, const int* in_sizes, int n_in,
                              void* d_out, int out_size, void* d_ws, size_t ws_size,
                              hipStream_t stream)
{
    const float* x   = (const float*)d_in[0];
    const int*   ei  = (const int*)  d_in[1];
    const float* As  = (const float*)d_in[2];
    const float* ws  = (const float*)d_in[3];
    const float* Wl1 = (const float*)d_in[4];
    const float* bl1 = (const float*)d_in[5];
    const float* Wr1 = (const float*)d_in[6];
    const float* Wl2 = (const float*)d_in[7];
    const float* bl2 = (const float*)d_in[8];
    const float* Wr2 = (const float*)d_in[9];
    float* out = (float*)d_out;

    // workspace (~25 MB)
    unsigned short* p      = (unsigned short*)d_ws;            // NN*NH bf16 (3.2 MB)
    float*          r      = (float*)(p + (size_t)NN * NH);    // NN*NH f32 (6.4 MB)
    float*          q      = r + (size_t)NN * NH;              // NN
    int*            bcnt   = (int*)(q + NN);                   // NBKT counts (3 KB)
    int*            fdirT  = bcnt + NBKT;                      // FD*NBF (0.6 MB)
    unsigned int*   gchunk = (unsigned int*)(fdirT + (size_t)FD * NBF); // NBF*CHUNK (6.4 MB)
    unsigned int*   bmem   = gchunk + (size_t)NBF * CHUNK;     // NBKT*CAP (8 MB)

    int nblk = NBF + NGT;                                      // 392: buckets 0..195, gemm 196..391
    k_fused<<<nblk, TB, 0, stream>>>(x, Wl1, Wr1, p, r, ei, As, ws, gchunk, fdirT);
    k_agg1<<<NBKT, 512, 0, stream>>>(fdirT, gchunk, bmem, bcnt, p, r, bl1, Wl2,
                                     bl2, Wr2, q, out);
    k_agg2<<<NBKT, 512, 0, stream>>>(bmem, bcnt, q, out);
}

// Round 10
// 154.893 us; speedup vs baseline: 2.0749x; 2.0749x over previous
//
#include <hip/hip_runtime.h>
#include <hip/hip_bf16.h>

constexpr int NN = 100000;   // nodes
constexpr int NE = 1600000;  // edges
constexpr int NF = 64;       // input features
constexpr int NH = 16;       // hidden

constexpr int NPB  = 128;                      // nodes per bucket (dst>>7 / dst&127)
constexpr int LB   = 7;                        // log2(NPB)
constexpr int NBKT = (NN + NPB - 1) / NPB;     // 782 buckets
constexpr int CAP  = 2560;                     // per-bucket edge capacity (mean 2046, +11 sigma)
constexpr int TB   = 512;                      // fused-kernel block size (8 waves)
constexpr int CHUNK = 8192;                    // edges per bucket-role block (16 edges/thread)
constexpr int NBF   = (NE + CHUNK - 1) / CHUNK;   // 196 bucket-role blocks / fragments
constexpr int NGT   = (NN + TB - 1) / TB;         // 196 gemm tiles (512 nodes each)
constexpr int FD = NBKT + 1;                      // directory rows (783): bucket starts + total

// LESSON LEDGER (do not re-try):
//  R1: GEMM 2-thread/node split -> doubles load requests, regresses (L2-latency-bound).
//  R2: TB=1024 k_fused -> 53-59 µs (vs 43). Fixed per-block costs don't amortize.
//  R4: CHUNK=6250 "exact CU balance" 512 blocks -> 62 µs. Placement theory wrong.
//  R6: zero-global-read pass B -> FETCH -10 MB, duration FLAT (pass-B reads are free).
//  R7: CHUNK=4096 -> 63 µs (fixed costs dominate at small chunks).
//  R8: hipLaunchCooperativeKernel -> container crash. NEVER cooperative here.
//  R9: LDS f32 unsafeAtomicAdd -> k_agg2 30 ms, k_agg1 183 µs. NEVER LDS float atomics.
//  R5: k_agg2 8 lanes/node -> +6 µs (degree-16 segments waste lanes).
// Best measured: THIS file's config = 155.689 µs (Round-3 bench).

// bucket-role LDS: srk 16K(u16) + lcnt 3.1K + fscan 3.1K + wsum 32B = ~22.8 KB
constexpr int SMEM_BYTES = CHUNK * 2 + NBKT * 4 + FD * 4 + 32;

__device__ __forceinline__ float bf16_to_f32(unsigned short u) {
    return __uint_as_float(((unsigned int)u) << 16);
}
__device__ __forceinline__ unsigned short f32_to_bf16(float f) {
    __hip_bfloat16 hb = __float2bfloat16(f);   // RNE
    return *reinterpret_cast<unsigned short*>(&hb);
}

// Fused front-end, 512 threads, 392 blocks: 0..195 bucket, 196..391 GEMM.
// GEMM role: 1 thread per node computes BOTH p = bf16(x@Wl1) and r = x@Wr1
// from one x-row read. Bucket role: counting-sort an 8192-edge chunk by
// bucket; wave-shuffle scan (1 barrier); fdir written TRANSPOSED
// ([bucket][frag]) so k_agg1's directory read is 2 coalesced rows.
// NOTE (R12 lesson): do NOT add per-thread accumulator arrays or float4
// weight indexing here — both spill (VGPR 56 -> 128, scratch traffic 670 MB).
__global__ __launch_bounds__(TB)
void k_fused(const float* __restrict__ x,
             const float* __restrict__ Wl1,
             const float* __restrict__ Wr1,
             unsigned short* __restrict__ p,
             float* __restrict__ r,
             const int* __restrict__ ei, const float* __restrict__ As,
             const float* __restrict__ ws,
             unsigned int* __restrict__ gchunk, int* __restrict__ fdirT)
{
    __shared__ __align__(16) char smem[SMEM_BYTES];
    int b    = blockIdx.x;
    int role = (b < NBF) ? 1 : 0;          // 1 = bucket, 0 = gemm
    int rb   = role ? b : b - NBF;
    int tid  = threadIdx.x;

    if (role == 0) {
        // ---- GEMM role: nodes rb*512 .. rb*512+511, 1 thread per node ----
        float* sW = (float*)smem;
        for (int i = tid; i < NF * NH; i += TB) {
            sW[i]           = Wl1[i];
            sW[NF * NH + i] = Wr1[i];
        }
        __syncthreads();

        int n = rb * TB + tid;
        if (n >= NN) return;

        float aL[NH], aR[NH];
#pragma unroll
        for (int j = 0; j < NH; ++j) { aL[j] = 0.f; aR[j] = 0.f; }

        const float4* xr = reinterpret_cast<const float4*>(x + (size_t)n * NF);
#pragma unroll
        for (int k4 = 0; k4 < NF / 4; ++k4) {
            float4 v = xr[k4];
            float xs[4] = {v.x, v.y, v.z, v.w};
#pragma unroll
            for (int t2 = 0; t2 < 4; ++t2) {
                const float* wl = &sW[(k4 * 4 + t2) * NH];
                const float* wr = &sW[NF * NH + (k4 * 4 + t2) * NH];
#pragma unroll
                for (int j = 0; j < NH; ++j) {
                    aL[j] = fmaf(xs[t2], wl[j], aL[j]);
                    aR[j] = fmaf(xs[t2], wr[j], aR[j]);
                }
            }
        }

        unsigned int pu[8];
#pragma unroll
        for (int j2 = 0; j2 < 8; ++j2)
            pu[j2] = (unsigned int)f32_to_bf16(aL[2*j2]) |
                     ((unsigned int)f32_to_bf16(aL[2*j2+1]) << 16);
        uint4* pp = reinterpret_cast<uint4*>(p + (size_t)n * NH);
        pp[0] = make_uint4(pu[0], pu[1], pu[2], pu[3]);
        pp[1] = make_uint4(pu[4], pu[5], pu[6], pu[7]);

        float4* rp = reinterpret_cast<float4*>(r + (size_t)n * NH);
#pragma unroll
        for (int j4 = 0; j4 < NH / 4; ++j4)
            rp[j4] = make_float4(aR[j4*4], aR[j4*4+1], aR[j4*4+2], aR[j4*4+3]);
    } else {
        // ---- Bucket role: edges rb*CHUNK .. +CHUNK ----
        unsigned short* srk  = (unsigned short*)smem;        // 16-bit rank, 0xFFFF=drop
        int* lcnt  = (int*)(smem + CHUNK * 2);               // NBKT counters
        int* fscan = lcnt + NBKT;                            // FD exclusive scan
        int* wsum  = fscan + FD;                             // 8 wave sums

        for (int i = tid; i < NBKT; i += TB) lcnt[i] = 0;
        __syncthreads();

        int base = rb * CHUNK;
        float w0 = ws[0], w1 = ws[1];

        // pass A: mask + per-bucket rank (the count atomic's return IS the rank)
#pragma unroll
        for (int j = 0; j < CHUNK / TB; ++j) {
            int idx = j * TB + tid;
            int e = base + idx;
            unsigned short rk = 0xFFFFu;
            if (e < NE) {
                float ewm = w0 * As[e] + w1 * As[NE + e];
                if (ewm != 0.f)
                    rk = (unsigned short)atomicAdd(&lcnt[ei[NE + e] >> LB], 1); // <8192
            }
            srk[idx] = rk;
        }
        __syncthreads();

        // exclusive scan of 782 counters: thread t owns entries 2t, 2t+1;
        // per-thread sums scanned with wave shuffles (1 barrier)
        {
            int loc[2]; int s0 = 0;
#pragma unroll
            for (int g = 0; g < 2; ++g) {
                int idx = tid * 2 + g;
                int v = (idx < NBKT) ? lcnt[idx] : 0;
                loc[g] = s0; s0 += v;
            }
            int lane = tid & 63, w = tid >> 6;
            int si = s0;
#pragma unroll
            for (int off = 1; off < 64; off <<= 1) {
                int u = __shfl_up(si, off);
                if (lane >= off) si += u;
            }
            if (lane == 63) wsum[w] = si;
            __syncthreads();
            int bse = 0;
            for (int i = 0; i < w; ++i) bse += wsum[i];
            int excl = bse + si - s0;      // exclusive scan of per-thread sums
#pragma unroll
            for (int g = 0; g < 2; ++g) {
                int idx = tid * 2 + g;
                if (idx < NBKT) fscan[idx] = excl + loc[g];
            }
            if (tid == TB - 1) fscan[NBKT] = bse + si;
        }
        __syncthreads();

        // export directory column rb (transposed: [bucket][fragment])
        for (int i = tid; i < FD; i += TB)
            fdirT[(size_t)i * NBF + rb] = fscan[i];

        // pass B: re-read ei (L2-hot, measured free in R6), place sorted into
        // the block-private region (dense, line-clean writes)
#pragma unroll
        for (int j = 0; j < CHUNK / TB; ++j) {
            int idx = j * TB + tid;
            unsigned short rk = srk[idx];
            if (rk != 0xFFFFu) {
                int e   = base + idx;
                int dst = ei[NE + e];
                int bk  = dst >> LB;
                gchunk[(size_t)rb * CHUNK + fscan[bk] + rk] =
                    ((unsigned)ei[e] << LB) | (unsigned)(dst & (NPB - 1));
            }
        }
    }
}

// Layer-1 aggregation, 512 threads (8 waves): gather this bucket's 196
// fragments via the transposed directory (2 coalesced rows), stage in LDS,
// counting-sort by dl, then 32 16-lane groups accumulate 4 nodes each in
// registers. dl-sorted list + offsets exported to bmem/gsoff for k_agg2.
// (R9 lesson: do NOT replace the sort+serial-gather with LDS float atomics.)
// Fused epilogue: h = relu(acc + r + bl1); q = h.Wl2; out = h.Wr2 + bl2.
__global__ __launch_bounds__(512)
void k_agg1(const int* __restrict__ fdirT, const unsigned int* __restrict__ gchunk,
            unsigned int* __restrict__ bmem,
            const unsigned short* __restrict__ p, const float* __restrict__ r,
            const float* __restrict__ bl1, const float* __restrict__ Wl2,
            const float* __restrict__ bl2, const float* __restrict__ Wr2,
            float* __restrict__ q, float* __restrict__ out,
            int* __restrict__ gsoff)
{
    __shared__ unsigned int sbm[CAP];       // 10 KB staged bucket
    __shared__ unsigned int ssorted[CAP];   // 10 KB sorted by dl
    __shared__ int fstart[NBF];             // fragment start in gchunk row
    __shared__ int foff[NBF + 1];           // exclusive scan of fragment sizes
    __shared__ int hist[NPB];
    __shared__ int soff[NPB + 1];
    __shared__ int wsum8[8];

    int b = blockIdx.x;
    int tid = threadIdx.x;
    if (tid < NPB) hist[tid] = 0;

    // fragment directory: coalesced rows b and b+1 of fdirT; wave-shuffle scan
    {
        int sz = 0;
        if (tid < NBF) {
            int s0 = fdirT[(size_t)b * NBF + tid];
            int s1 = fdirT[(size_t)(b + 1) * NBF + tid];
            fstart[tid] = s0;
            sz = s1 - s0;
        }
        int lane = tid & 63, w = tid >> 6;
        int si = sz;
#pragma unroll
        for (int off = 1; off < 64; off <<= 1) {
            int u = __shfl_up(si, off);
            if (lane >= off) si += u;
        }
        if (lane == 63) wsum8[w] = si;
        __syncthreads();
        int bse = 0;
        for (int i = 0; i < w; ++i) bse += wsum8[i];
        if (tid < NBF) foff[tid] = bse + si - sz;   // exclusive
        if (tid == 511) foff[NBF] = bse + si;
    }
    __syncthreads();

    int cnt = min(foff[NBF], CAP);

    // stage: 32 16-lane groups; contiguous reads from gchunk
    {
        int grp = tid >> 4, k = tid & 15;
        for (int f = grp; f < NBF; f += 32) {
            int o  = foff[f];
            int sz = foff[f + 1] - o;
            int s  = fstart[f];
            const unsigned int* src = gchunk + (size_t)f * CHUNK + s;
            int lim = min(sz, CAP - o);
            for (int j = k; j < lim; j += 16)
                sbm[o + j] = src[j];
        }
    }
    __syncthreads();

    // histogram by dl; the atomic's return value is the rank
    int rk[CAP / 512];
#pragma unroll
    for (int j = 0; j < CAP / 512; ++j) {
        int i = j * 512 + tid;
        if (i < cnt)
            rk[j] = atomicAdd(&hist[sbm[i] & (NPB - 1)], 1);
    }
    __syncthreads();

    // exclusive scan of 128 counters (wave-shuffle)
    {
        int v = (tid < NPB) ? hist[tid] : 0;
        int lane = tid & 63, w = tid >> 6;
        int si = v;
#pragma unroll
        for (int off = 1; off < 64; off <<= 1) {
            int u = __shfl_up(si, off);
            if (lane >= off) si += u;
        }
        if (lane == 63) wsum8[w] = si;
        __syncthreads();
        int bse = 0;
        for (int i = 0; i < w; ++i) bse += wsum8[i];
        if (tid < NPB) soff[tid + 1] = bse + si;     // inclusive
        if (tid == 0) soff[0] = 0;
    }
    __syncthreads();

    // rank-scatter into ssorted
#pragma unroll
    for (int j = 0; j < CAP / 512; ++j) {
        int i = j * 512 + tid;
        if (i < cnt) {
            unsigned int w = sbm[i];
            ssorted[soff[w & (NPB - 1)] + rk[j]] = w;
        }
    }
    __syncthreads();

    // export sorted list (coalesced, line-aligned rows) + offsets for agg2
    for (int i = tid; i < cnt; i += 512)
        bmem[(size_t)b * CAP + i] = ssorted[i];
    if (tid < NPB + 1)
        gsoff[(size_t)b * (NPB + 1) + tid] = soff[tid];

    // register accumulation — group g owns nodes 4g..4g+3, lane k feature k
    int g = tid >> 4, k = tid & 15;
    int n0 = b * NPB;
#pragma unroll
    for (int jj = 0; jj < 4; ++jj) {
        int nl = g * 4 + jj;
        int s = soff[nl], e = soff[nl + 1];
        float a = 0.f;
        int i = s;
        for (; i + 3 < e; i += 4) {
            unsigned w0 = ssorted[i], w1 = ssorted[i+1], w2 = ssorted[i+2], w3 = ssorted[i+3];
            float v0 = bf16_to_f32(p[(size_t)(w0 >> LB) * NH + k]);
            float v1 = bf16_to_f32(p[(size_t)(w1 >> LB) * NH + k]);
            float v2 = bf16_to_f32(p[(size_t)(w2 >> LB) * NH + k]);
            float v3 = bf16_to_f32(p[(size_t)(w3 >> LB) * NH + k]);
            a += (v0 + v1) + (v2 + v3);
        }
        for (; i < e; ++i)
            a += bf16_to_f32(p[(size_t)(ssorted[i] >> LB) * NH + k]);

        int n = n0 + nl;
        if (n < NN) {
            float h = a + r[(size_t)n * NH + k] + bl1[k];
            h = h > 0.f ? h : 0.f;
            float qv = h * Wl2[k];
            float sv = h * Wr2[k];
#pragma unroll
            for (int m = 8; m >= 1; m >>= 1) {
                qv += __shfl_xor(qv, m);
                sv += __shfl_xor(sv, m);
            }
            if (k == 0) {
                q[n]   = qv;
                out[n] = sv + bl2[0];
            }
        }
    }
}

// Layer-2 aggregation: 4 lanes per node stride the node's dl-sorted segment
// (coalesced bmem reads, 4 gather chains in flight per node), then combine
// with two shuffles. q is 400 KB, L2-resident. (R5 lesson: 8 lanes/node
// regressed ~6 µs; R9 lesson: LDS-atomic rewrite regressed 1700x.)
__global__ __launch_bounds__(256)
void k_agg2(const int* __restrict__ gsoff, const unsigned int* __restrict__ bmem,
            const float* __restrict__ q, float* __restrict__ out)
{
    int t = blockIdx.x * 256 + threadIdx.x;
    int n = t >> 2;
    int sub = t & 3;
    if (n >= NN) return;
    int b  = n >> LB;
    int dl = n & (NPB - 1);
    int s = gsoff[(size_t)b * (NPB + 1) + dl];
    int e = gsoff[(size_t)b * (NPB + 1) + dl + 1];
    const unsigned int* bm = bmem + (size_t)b * CAP;

    float a = 0.f;
    for (int i = s + sub; i < e; i += 4)
        a += q[bm[i] >> LB];
    a += __shfl_xor(a, 1);
    a += __shfl_xor(a, 2);
    if (sub == 0) out[n] += a;
}

extern "C" void kernel_launch(void* const* d_in, const int* in_sizes, int n_in,
                              void* d_out, int out_size, void* d_ws, size_t ws_size,
                              hipStream_t stream)
{
    const float* x   = (const float*)d_in[0];
    const int*   ei  = (const int*)  d_in[1];
    const float* As  = (const float*)d_in[2];
    const float* ws  = (const float*)d_in[3];
    const float* Wl1 = (const float*)d_in[4];
    const float* bl1 = (const float*)d_in[5];
    const float* Wr1 = (const float*)d_in[6];
    const float* Wl2 = (const float*)d_in[7];
    const float* bl2 = (const float*)d_in[8];
    const float* Wr2 = (const float*)d_in[9];
    float* out = (float*)d_out;

    // workspace (~25 MB)
    unsigned short* p      = (unsigned short*)d_ws;            // NN*NH bf16 (3.2 MB)
    float*          r      = (float*)(p + (size_t)NN * NH);    // NN*NH f32 (6.4 MB)
    float*          q      = r + (size_t)NN * NH;              // NN
    int*            gsoff  = (int*)(q + NN);                   // NBKT*(NPB+1) (0.4 MB)
    int*            fdirT  = gsoff + (size_t)NBKT * (NPB + 1); // FD*NBF (0.6 MB)
    unsigned int*   gchunk = (unsigned int*)(fdirT + (size_t)FD * NBF); // NBF*CHUNK (6.4 MB)
    unsigned int*   bmem   = gchunk + (size_t)NBF * CHUNK;     // NBKT*CAP (8 MB)

    int nblk = NBF + NGT;                                      // 392: buckets 0..195, gemm 196..391
    k_fused<<<nblk, TB, 0, stream>>>(x, Wl1, Wr1, p, r, ei, As, ws, gchunk, fdirT);
    k_agg1<<<NBKT, 512, 0, stream>>>(fdirT, gchunk, bmem, p, r, bl1, Wl2, bl2, Wr2,
                                     q, out, gsoff);
    k_agg2<<<(NN * 4 + 255) / 256, 256, 0, stream>>>(gsoff, bmem, q, out);
}